// Round 2
// baseline (130.725 us; speedup 1.0000x reference)
//
#include <hip/hip_runtime.h>

typedef unsigned short u16;
typedef unsigned int u32;
typedef unsigned long long u64;

#define VOCAB 50000
#define BATCH 2048
#define NTOP 64
#define RHO 0.1f

#define KSPLIT 32
#define CHUNK 1568          // 49*32; chunk 31 covers 48608..50000 (43 full + 16-k tail)
#define NKB 1563            // ceil(50016/32) blocks of 32 k, zero-padded past 50000
#define GPC 12504           // 4-element groups per topic row (50016/4)

typedef short bf16x8 __attribute__((ext_vector_type(8)));
typedef float f32x4 __attribute__((ext_vector_type(4)));

__device__ __forceinline__ u16 f32_to_bf16(float f) {
  u32 u = __builtin_bit_cast(u32, f);
  return (u16)((u + 0x8000u) >> 16);
}
__device__ __forceinline__ u32 pack2(float a, float b) {
  return (u32)f32_to_bf16(a) | ((u32)f32_to_bf16(b) << 16);
}
__device__ __forceinline__ u32 cvtpk(float lo, float hi) {
  u32 r;
  asm volatile("v_cvt_pk_bf16_f32 %0, %1, %2" : "=v"(r) : "v"(lo), "v"(hi));
  return r;
}
union frag_cast { u32 w[4]; bf16x8 v; };

// Kernel 1: zero s; permute beta f32 -> bf16 into MFMA-fragment order.
// Layout: element(bp) = kb*2048 + col*32 + p, where within a 32-k block the
// position p maps to k-offset j: p = fk*8 + e  ->  j = (e<4)? fk*4+e : 16+fk*4+(e-4).
// Lane (fr,fk) of the GEMM then reads its whole B fragment as ONE 16B load at
// col*32 + fk*8, and a full wave's load covers 1024 contiguous bytes.
__global__ void ctm_prep(const float* __restrict__ beta, u16* __restrict__ bp,
                         float* __restrict__ s) {
  int i = blockIdx.x * blockDim.x + threadIdx.x;
  int stride = gridDim.x * blockDim.x;
  for (int j = i; j < (BATCH * NTOP / 4); j += stride)
    ((float4*)s)[j] = make_float4(0.f, 0.f, 0.f, 0.f);
  for (int j = i; j < NTOP * GPC; j += stride) {
    int col = j / GPC;
    int g = j - col * GPC;
    int k = g * 4;                      // 4 consecutive k, same fk-group, same half
    float4 v = make_float4(0.f, 0.f, 0.f, 0.f);
    if (k < VOCAB)                      // VOCAB%4==0: group fully valid or fully pad
      v = *(const float4*)(beta + (u64)col * VOCAB + k);
    int kb = k >> 5;
    int jj = k & 31;
    int pbase = ((jj & 15) >> 2) * 8 + ((jj & 16) ? 4 : 0);
    u32 lo = pack2(v.x, v.y), hi = pack2(v.z, v.w);
    *(uint2*)(bp + (u64)kb * 2048 + col * 32 + pbase) = make_uint2(lo, hi);
  }
}

// Kernel 2: barrier-free streaming GEMM. No LDS. Each wave owns 16 rows of x;
// A fragments loaded directly from global (wave = 16 rows x 64B contiguous per
// instruction), converted in-reg; B fragments are single 16B loads from the
// permuted beta (wave = 1024B contiguous, L2-resident per k-chunk).
__global__ void __launch_bounds__(256, 4) ctm_gemm(const float* __restrict__ x,
                                                   const u16* __restrict__ bp,
                                                   float* __restrict__ s) {
  const int t = threadIdx.x;
  const int l = t & 63;
  const int w = t >> 6;
  const int fr = l & 15;
  const int fk = l >> 4;

  const int k0 = blockIdx.x * CHUNK;
  const int kend = (k0 + CHUNK < VOCAB) ? (k0 + CHUNK) : VOCAB;
  const int row = blockIdx.y * 64 + w * 16 + fr;

  const float* ax = x + (u64)row * VOCAB + k0 + fk * 4;
  const u16* bb = bp + (u64)(k0 >> 5) * 2048 + fr * 32 + fk * 8;

  const int nfull = (kend - k0) >> 5;
  const bool tail = ((kend - k0) & 31) != 0;

  f32x4 acc[4] = {{0.f,0.f,0.f,0.f},{0.f,0.f,0.f,0.f},{0.f,0.f,0.f,0.f},{0.f,0.f,0.f,0.f}};

  #pragma unroll 2
  for (int st = 0; st < nfull; ++st) {
    const float4* ap = (const float4*)ax;
    float4 a0 = ap[0];                  // k = ks0 + fk*4 + 0..3
    float4 a1 = ap[4];                  // k = ks0 + 16 + fk*4 + 0..3
    frag_cast ua;
    ua.w[0] = cvtpk(a0.x, a0.y);
    ua.w[1] = cvtpk(a0.z, a0.w);
    ua.w[2] = cvtpk(a1.x, a1.y);
    ua.w[3] = cvtpk(a1.z, a1.w);
    #pragma unroll
    for (int n = 0; n < 4; ++n) {       // col = n*16 + fr -> +n*512 u16 = +n*1024B (imm)
      bf16x8 bf = *(const bf16x8*)(bb + n * 512);
      acc[n] = __builtin_amdgcn_mfma_f32_16x16x32_bf16(ua.v, bf, acc[n], 0, 0, 0);
    }
    ax += 32;
    bb += 2048;
  }

  if (tail) {                           // last chunk only: 16 valid k (50000%32==16)
    const int ks0 = k0 + (nfull << 5);
    float av[8];
    #pragma unroll
    for (int e = 0; e < 8; ++e) {
      int k = ks0 + ((e < 4) ? (fk * 4 + e) : (16 + fk * 4 + (e - 4)));
      av[e] = (k < VOCAB) ? x[(u64)row * VOCAB + k] : 0.f;
    }
    frag_cast ua;
    ua.w[0] = cvtpk(av[0], av[1]);
    ua.w[1] = cvtpk(av[2], av[3]);
    ua.w[2] = cvtpk(av[4], av[5]);
    ua.w[3] = cvtpk(av[6], av[7]);
    #pragma unroll
    for (int n = 0; n < 4; ++n) {       // B zero-padded past 50000 by prep
      bf16x8 bf = *(const bf16x8*)(bb + n * 512);
      acc[n] = __builtin_amdgcn_mfma_f32_16x16x32_bf16(ua.v, bf, acc[n], 0, 0, 0);
    }
  }

  // C/D layout (verified R1): col = l&15 (=fr), row_in_tile = fk*4 + r
  const int orow = blockIdx.y * 64 + w * 16 + fk * 4;
  #pragma unroll
  for (int n = 0; n < 4; ++n) {
    #pragma unroll
    for (int r = 0; r < 4; ++r)
      atomicAdd(&s[(orow + r) * NTOP + ((n << 4) | fr)], acc[n][r]);
  }
}

// Kernel 3: out[b,k] = s[b,k] + mu[k] + RHO*(sum_j theta[k,j]*s[b,j] - theta[k,k]*s[b,k])
__global__ void __launch_bounds__(256) ctm_epi(const float* __restrict__ s,
                                               const float* __restrict__ theta,
                                               const float* __restrict__ mu,
                                               float* __restrict__ out) {
  __shared__ float thT[NTOP * NTOP];    // thT[j*64+k] = theta[k][j]
  __shared__ float sb[8 * NTOP];
  const int t = threadIdx.x;
  const int r0 = blockIdx.x * 8;

  #pragma unroll
  for (int i = 0; i < 16; ++i) {
    int e = i * 256 + t;
    thT[(e & 63) * 64 + (e >> 6)] = theta[e];
  }
  sb[t] = s[r0 * 64 + t];
  sb[t + 256] = s[r0 * 64 + 256 + t];
  __syncthreads();

  const int k = t & 63;
  const int rl = t >> 6;
  const float muk = mu[k];
  const float diag = thT[k * 64 + k];
  #pragma unroll
  for (int rr = 0; rr < 2; ++rr) {
    const int r = rl + rr * 4;
    const float* srow = &sb[r * 64];
    float accv = 0.f;
    #pragma unroll 8
    for (int j = 0; j < 64; ++j)
      accv += thT[j * 64 + k] * srow[j];
    const float sv = srow[k];
    out[(r0 + r) * 64 + k] = sv + muk + RHO * (accv - diag * sv);
  }
}

extern "C" void kernel_launch(void* const* d_in, const int* in_sizes, int n_in,
                              void* d_out, int out_size, void* d_ws, size_t ws_size,
                              hipStream_t stream) {
  const float* x = (const float*)d_in[0];
  const float* beta = (const float*)d_in[1];
  const float* theta = (const float*)d_in[2];
  const float* mu = (const float*)d_in[3];
  float* out = (float*)d_out;

  // ws: [0, 6402048) permuted beta bf16 (NKB*2048*2B); s at +6403072 (512KB)
  u16* bp = (u16*)d_ws;
  float* s = (float*)((char*)d_ws + 6403072u);

  ctm_prep<<<2048, 256, 0, stream>>>(beta, bp, s);
  ctm_gemm<<<dim3(KSPLIT, BATCH / 64), 256, 0, stream>>>(x, bp, s);
  ctm_epi<<<BATCH / 8, 256, 0, stream>>>(s, theta, mu, out);
}

// Round 3
// 111.727 us; speedup vs baseline: 1.1700x; 1.1700x over previous
//
#include <hip/hip_runtime.h>

typedef unsigned short u16;
typedef unsigned int u32;
typedef unsigned long long u64;

#define VOCAB 50000
#define BATCH 2048
#define NTOP 64
#define RHO 0.1f

#define KSPLIT 32
#define CHUNK 1568          // 12x128 + 32; chunk 31: 48608..50000 = 10x128 + 112
#define NKB 1568            // padded 32-k blocks (covers 50176, zero-padded past 50000)
#define GPC 12544           // 50176/4 groups per topic row
#define KSTEP 128

typedef short bf16x8 __attribute__((ext_vector_type(8)));
typedef float f32x4 __attribute__((ext_vector_type(4)));

__device__ __forceinline__ u16 f32_to_bf16(float f) {
  u32 u = __builtin_bit_cast(u32, f);
  return (u16)((u + 0x8000u) >> 16);
}
__device__ __forceinline__ u32 pack2(float a, float b) {
  return (u32)f32_to_bf16(a) | ((u32)f32_to_bf16(b) << 16);
}
__device__ __forceinline__ u32 cvtpk(float lo, float hi) {
  u32 r;
  asm volatile("v_cvt_pk_bf16_f32 %0, %1, %2" : "=v"(r) : "v"(lo), "v"(hi));
  return r;
}
union frag_cast { u32 w[4]; bf16x8 v; };

// Kernel 1: permute beta f32 -> bf16 MFMA-fragment order (R2-proven layout):
// element(bp) = kb*2048 + col*32 + p;  p = fk*8 + e, e<4 -> k=kb*32+fk*4+e,
// e>=4 -> k=kb*32+16+fk*4+(e-4). Zero-padded for k in [50000, 50176).
__global__ void ctm_prep(const float* __restrict__ beta, u16* __restrict__ bp) {
  int i = blockIdx.x * blockDim.x + threadIdx.x;
  int stride = gridDim.x * blockDim.x;
  for (int j = i; j < NTOP * GPC; j += stride) {
    int col = j / GPC;
    int g = j - col * GPC;
    int k = g * 4;
    float4 v = make_float4(0.f, 0.f, 0.f, 0.f);
    if (k < VOCAB)
      v = *(const float4*)(beta + (u64)col * VOCAB + k);
    int kb = k >> 5;
    int jj = k & 31;
    int pbase = ((jj & 15) >> 2) * 8 + ((jj & 16) ? 4 : 0);
    u32 lo = pack2(v.x, v.y), hi = pack2(v.z, v.w);
    *(uint2*)(bp + (u64)kb * 2048 + col * 32 + pbase) = make_uint2(lo, hi);
  }
}

// Kernel 2: LDS-staged GEMM, 64 rows x full-N=64 per block, KSTEP=128.
// A: f32 global (512B-contiguous runs) -> cvt -> swizzled LDS [row][k].
// B: global_load_lds of permuted bp (linear dest). Partials to sp (no atomics).
__global__ void __launch_bounds__(256, 4) ctm_gemm(const float* __restrict__ x,
                                                   const u16* __restrict__ bp,
                                                   float* __restrict__ sp) {
  __shared__ u16 ldsA[64 * KSTEP];   // 16KB: byte = row*256 + (2*(k-ks0) ^ ((row&7)<<4))
  __shared__ u16 ldsB[4 * 2048];     // 16KB: linear image of bp kb-blocks [kb][col][p]

  const int t = threadIdx.x;
  const int l = t & 63;
  const int w = t >> 6;
  const int fr = l & 15;
  const int fk = l >> 4;

  const int bx = blockIdx.x;
  const int k0 = bx * CHUNK;
  const int kend = (k0 + CHUNK < VOCAB) ? (k0 + CHUNK) : VOCAB;
  const int row0 = blockIdx.y * 64;
  const int nfull = (kend - k0) >> 7;

  // A staging map: c = t&31 -> k quad, srow = t>>5 -> rows srow + rr*8
  const int c = t & 31;
  const int srow = t >> 5;
  const float* xbase = x + (u64)(row0 + srow) * VOCAB + k0 + c * 4;
  const u32 aws = ((u32)(c * 8)) ^ ((u32)srow << 4);   // (srow+rr*8)&7 == srow

  // B staging: wave-uniform LDS dest quarter; per-lane global source
  const u32 bofs = (u32)(w << 12);

  // fragment read constants
  const int arow = w * 16 + fr;
  const u32 arb = (u32)(arow * 256);
  const u32 aswz = (u32)((arow & 7) << 4);

  f32x4 acc[4] = {{0.f,0.f,0.f,0.f},{0.f,0.f,0.f,0.f},{0.f,0.f,0.f,0.f},{0.f,0.f,0.f,0.f}};

  for (int st = 0; st <= nfull; ++st) {
    const int ks0 = k0 + st * KSTEP;
    const int rem = ((kend - ks0) < KSTEP) ? (kend - ks0) : KSTEP;  // mult of 4
    if (rem <= 0) break;

    // B tile first (async direct-to-LDS; bp padded so full 4-kb read is safe)
    const u64 bsrc = (u64)(ks0 >> 5) * 4096u;
    #pragma unroll
    for (int i = 0; i < 4; ++i) {
      __builtin_amdgcn_global_load_lds(
          (const __attribute__((address_space(1))) void*)
              ((const char*)bp + bsrc + bofs + (u32)(i * 1024) + (u32)(l * 16)),
          (__attribute__((address_space(3))) void*)((char*)ldsB + bofs + (u32)(i * 1024)),
          16, 0, 0);
    }

    // A tile: 8 passes x (2 rows x 512B contiguous per wave-instruction)
    if (rem == KSTEP) {
      #pragma unroll
      for (int rr = 0; rr < 8; ++rr) {
        float4 v = *(const float4*)(xbase + (u64)rr * (8 * VOCAB) + st * KSTEP);
        u32 w0 = cvtpk(v.x, v.y), w1 = cvtpk(v.z, v.w);
        *(uint2*)((char*)ldsA + (u32)(srow * 256) + (u32)(rr * 2048) + aws) =
            make_uint2(w0, w1);
      }
    } else {
      #pragma unroll
      for (int rr = 0; rr < 8; ++rr) {
        float4 v = make_float4(0.f, 0.f, 0.f, 0.f);
        if (c * 4 < rem)
          v = *(const float4*)(xbase + (u64)rr * (8 * VOCAB) + st * KSTEP);
        u32 w0 = cvtpk(v.x, v.y), w1 = cvtpk(v.z, v.w);
        *(uint2*)((char*)ldsA + (u32)(srow * 256) + (u32)(rr * 2048) + aws) =
            make_uint2(w0, w1);
      }
    }

    __syncthreads();

    #pragma unroll
    for (int s = 0; s < 4; ++s) {
      const u32 o1 = ((u32)(s * 64 + fk * 8)) ^ aswz;
      const u32 o2 = ((u32)(s * 64 + 32 + fk * 8)) ^ aswz;
      uint2 d1 = *(const uint2*)((const char*)ldsA + arb + o1);
      uint2 d2 = *(const uint2*)((const char*)ldsA + arb + o2);
      frag_cast ua;
      ua.w[0] = d1.x; ua.w[1] = d1.y; ua.w[2] = d2.x; ua.w[3] = d2.y;
      #pragma unroll
      for (int n = 0; n < 4; ++n) {
        bf16x8 bf = *(const bf16x8*)((const char*)ldsB +
                                     (u32)(s * 4096 + (n * 16 + fr) * 64 + fk * 16));
        acc[n] = __builtin_amdgcn_mfma_f32_16x16x32_bf16(ua.v, bf, acc[n], 0, 0, 0);
      }
    }

    __syncthreads();
  }

  // partials: sp[bx][row][col], row = w*16 + fk*4 + r, col = n*16 + fr
  float* spb = sp + (u64)bx * (BATCH * NTOP);
  const int orow = row0 + w * 16 + fk * 4;
  #pragma unroll
  for (int n = 0; n < 4; ++n) {
    #pragma unroll
    for (int r = 0; r < 4; ++r)
      spb[(orow + r) * NTOP + ((n << 4) | fr)] = acc[n][r];
  }
}

// Kernel 3: reduce 32 partials, then out = s + mu + RHO*(s @ theta_offdiag^T)
__global__ void __launch_bounds__(256) ctm_epi(const float* __restrict__ sp,
                                               const float* __restrict__ theta,
                                               const float* __restrict__ mu,
                                               float* __restrict__ out) {
  __shared__ float thT[NTOP * NTOP];   // thT[j*64+k] = theta[k][j]
  __shared__ float sb[8 * NTOP];
  const int t = threadIdx.x;
  const int r0 = blockIdx.x * 8;

  #pragma unroll
  for (int i = 0; i < 16; ++i) {
    int e = i * 256 + t;
    thT[(e & 63) * 64 + (e >> 6)] = theta[e];
  }

  const int k = t & 63;
  const int rl = t >> 6;
  #pragma unroll
  for (int rr = 0; rr < 2; ++rr) {
    const int r = rl + rr * 4;
    float sum = 0.f;
    #pragma unroll
    for (int cc = 0; cc < KSPLIT; ++cc)
      sum += sp[(u64)cc * (BATCH * NTOP) + (r0 + r) * NTOP + k];
    sb[r * 64 + k] = sum;
  }
  __syncthreads();

  const float muk = mu[k];
  const float diag = thT[k * 64 + k];
  #pragma unroll
  for (int rr = 0; rr < 2; ++rr) {
    const int r = rl + rr * 4;
    const float* srow = &sb[r * 64];
    float accv = 0.f;
    #pragma unroll 8
    for (int j = 0; j < 64; ++j)
      accv += thT[j * 64 + k] * srow[j];
    const float sv = srow[k];
    out[(r0 + r) * 64 + k] = sv + muk + RHO * (accv - diag * sv);
  }
}

extern "C" void kernel_launch(void* const* d_in, const int* in_sizes, int n_in,
                              void* d_out, int out_size, void* d_ws, size_t ws_size,
                              hipStream_t stream) {
  const float* x = (const float*)d_in[0];
  const float* beta = (const float*)d_in[1];
  const float* theta = (const float*)d_in[2];
  const float* mu = (const float*)d_in[3];
  float* out = (float*)d_out;

  // ws: [0, 6422528) bp bf16; [6422528, +16777216) s_part f32 (every element
  // written each launch; no zero-init needed anywhere).
  u16* bp = (u16*)d_ws;
  float* sp = (float*)((char*)d_ws + 6422528u);

  ctm_prep<<<1568, 256, 0, stream>>>(beta, bp);
  ctm_gemm<<<dim3(KSPLIT, BATCH / 64), 256, 0, stream>>>(x, bp, sp);
  ctm_epi<<<BATCH / 8, 256, 0, stream>>>(sp, theta, mu, out);
}

// Round 4
// 109.659 us; speedup vs baseline: 1.1921x; 1.0189x over previous
//
#include <hip/hip_runtime.h>

typedef unsigned short u16;
typedef unsigned int u32;
typedef unsigned long long u64;

#define VOCAB 50000
#define BATCH 2048
#define NTOP 64
#define RHO 0.1f

#define KSPLIT 32
#define CHUNK 1568          // 24x64 + 32; chunk 31: 48608..50000 = 21x64 + 48
#define KSTEP 64

typedef short bf16x4 __attribute__((ext_vector_type(4)));
typedef short bf16x8 __attribute__((ext_vector_type(8)));
typedef float f32x4 __attribute__((ext_vector_type(4)));

__device__ __forceinline__ u32 cvtpk(float lo, float hi) {
  u32 r;
  asm volatile("v_cvt_pk_bf16_f32 %0, %1, %2" : "=v"(r) : "v"(lo), "v"(hi));
  return r;
}
union frag_cast { bf16x4 h[2]; bf16x8 v; };

// Fused GEMM: s_part[bx] = x[rows, chunk bx] @ beta[:, chunk bx]^T (bf16 MFMA).
// Double-buffered LDS, ONE barrier per k-step, reg-staged A and B so the
// compiler emits per-use vmcnt instead of a pre-barrier vmcnt(0) drain.
// LDS layout (R1-proven): tile [r][k] bf16, byte = r*128 + (2k ^ ((r&7)<<4)).
__global__ void __launch_bounds__(256, 4) ctm_gemm(const float* __restrict__ x,
                                                   const float* __restrict__ beta,
                                                   float* __restrict__ sp) {
  __shared__ u16 ldsA[2][64 * KSTEP];   // 8KB per buffer
  __shared__ u16 ldsB[2][64 * KSTEP];

  const int t = threadIdx.x;
  const int l = t & 63;
  const int w = t >> 6;
  const int fr = l & 15;
  const int fk = l >> 4;

  const int bx = blockIdx.x;
  const int k0 = bx * CHUNK;
  const int kend = (k0 + CHUNK < VOCAB) ? (k0 + CHUNK) : VOCAB;
  const int row0 = blockIdx.y * 64;
  const int nsteps = (kend - k0 + KSTEP - 1) >> 6;

  // Staging map: srow = t>>4 handles rows {srow, srow+16, srow+32, srow+48},
  // c = t&15 is the k-quad. Per wave-instruction: 4 rows x 256B contiguous.
  const int c = t & 15;
  const int srow = t >> 4;
  const float* xb = x + (u64)(row0 + srow) * VOCAB + k0 + c * 4;
  const float* betab = beta + (u64)srow * VOCAB + k0 + c * 4;   // beta row = B col
  // (srow + 16j) & 7 == srow & 7, so one swizzle constant serves all 4 rows
  const u32 wofs = (u32)(srow * 128) + (((u32)(c * 8)) ^ ((u32)((srow & 7) << 4)));

  // Fragment-read constants
  const int arow = w * 16 + fr;
  const u32 arb = (u32)(arow * 128);
  const u32 aswz = (u32)((arow & 7) << 4);

  f32x4 acc[4] = {{0.f,0.f,0.f,0.f},{0.f,0.f,0.f,0.f},{0.f,0.f,0.f,0.f},{0.f,0.f,0.f,0.f}};

  // ---- prologue: stage step 0 into buffer 0 ----
  {
    const int rem = kend - k0 < KSTEP ? kend - k0 : KSTEP;
    const bool m = (c * 4) < rem;
    float4 a0 = make_float4(0,0,0,0), a1 = a0, a2 = a0, a3 = a0;
    float4 b0 = a0, b1 = a0, b2 = a0, b3 = a0;
    if (m) {
      a0 = *(const float4*)(xb);               b0 = *(const float4*)(betab);
      a1 = *(const float4*)(xb + 16 * VOCAB);  b1 = *(const float4*)(betab + 16 * VOCAB);
      a2 = *(const float4*)(xb + 32 * VOCAB);  b2 = *(const float4*)(betab + 32 * VOCAB);
      a3 = *(const float4*)(xb + 48 * VOCAB);  b3 = *(const float4*)(betab + 48 * VOCAB);
    }
    *(uint2*)((char*)ldsA[0] + wofs)        = make_uint2(cvtpk(a0.x,a0.y), cvtpk(a0.z,a0.w));
    *(uint2*)((char*)ldsA[0] + wofs + 2048) = make_uint2(cvtpk(a1.x,a1.y), cvtpk(a1.z,a1.w));
    *(uint2*)((char*)ldsA[0] + wofs + 4096) = make_uint2(cvtpk(a2.x,a2.y), cvtpk(a2.z,a2.w));
    *(uint2*)((char*)ldsA[0] + wofs + 6144) = make_uint2(cvtpk(a3.x,a3.y), cvtpk(a3.z,a3.w));
    *(uint2*)((char*)ldsB[0] + wofs)        = make_uint2(cvtpk(b0.x,b0.y), cvtpk(b0.z,b0.w));
    *(uint2*)((char*)ldsB[0] + wofs + 2048) = make_uint2(cvtpk(b1.x,b1.y), cvtpk(b1.z,b1.w));
    *(uint2*)((char*)ldsB[0] + wofs + 4096) = make_uint2(cvtpk(b2.x,b2.y), cvtpk(b2.z,b2.w));
    *(uint2*)((char*)ldsB[0] + wofs + 6144) = make_uint2(cvtpk(b3.x,b3.y), cvtpk(b3.z,b3.w));
  }
  __syncthreads();

  // ---- main loop: one barrier per step ----
  for (int st = 0; st < nsteps; ++st) {
    const int cb = st & 1;
    const bool have_next = (st + 1) < nsteps;

    // 1) issue next step's global loads EARLY (latency hides under compute)
    float4 a0, a1, a2, a3, b0, b1, b2, b3;
    if (have_next) {
      const int ks = (st + 1) << 6;
      const int rem = kend - k0 - ks;
      const bool m = (c * 4) < rem;
      a0 = a1 = a2 = a3 = make_float4(0,0,0,0);
      b0 = b1 = b2 = b3 = make_float4(0,0,0,0);
      if (m) {
        const float* xp = xb + ks;
        const float* bp2 = betab + ks;
        a0 = *(const float4*)(xp);               b0 = *(const float4*)(bp2);
        a1 = *(const float4*)(xp + 16 * VOCAB);  b1 = *(const float4*)(bp2 + 16 * VOCAB);
        a2 = *(const float4*)(xp + 32 * VOCAB);  b2 = *(const float4*)(bp2 + 32 * VOCAB);
        a3 = *(const float4*)(xp + 48 * VOCAB);  b3 = *(const float4*)(bp2 + 48 * VOCAB);
      }
    }

    // 2) compute current buffer (ds_read + 8 MFMA)
    const char* bufA = (const char*)ldsA[cb];
    const char* bufB = (const char*)ldsB[cb];
    #pragma unroll
    for (int s = 0; s < 2; ++s) {
      const u32 in0 = (u32)(s * 64 + fk * 8);
      const u32 in1 = in0 + 32;
      frag_cast ua;
      ua.h[0] = *(const bf16x4*)(bufA + arb + (in0 ^ aswz));
      ua.h[1] = *(const bf16x4*)(bufA + arb + (in1 ^ aswz));
      #pragma unroll
      for (int n = 0; n < 4; ++n) {
        const int bcol = (n << 4) | fr;
        const u32 brb = (u32)(bcol * 128);
        const u32 bswz = (u32)((bcol & 7) << 4);
        frag_cast ub;
        ub.h[0] = *(const bf16x4*)(bufB + brb + (in0 ^ bswz));
        ub.h[1] = *(const bf16x4*)(bufB + brb + (in1 ^ bswz));
        acc[n] = __builtin_amdgcn_mfma_f32_16x16x32_bf16(ua.v, ub.v, acc[n], 0, 0, 0);
      }
    }

    // 3) convert + LDS-write next buffer, single barrier
    if (have_next) {
      char* nA = (char*)ldsA[cb ^ 1];
      char* nB = (char*)ldsB[cb ^ 1];
      *(uint2*)(nA + wofs)        = make_uint2(cvtpk(a0.x,a0.y), cvtpk(a0.z,a0.w));
      *(uint2*)(nA + wofs + 2048) = make_uint2(cvtpk(a1.x,a1.y), cvtpk(a1.z,a1.w));
      *(uint2*)(nA + wofs + 4096) = make_uint2(cvtpk(a2.x,a2.y), cvtpk(a2.z,a2.w));
      *(uint2*)(nA + wofs + 6144) = make_uint2(cvtpk(a3.x,a3.y), cvtpk(a3.z,a3.w));
      *(uint2*)(nB + wofs)        = make_uint2(cvtpk(b0.x,b0.y), cvtpk(b0.z,b0.w));
      *(uint2*)(nB + wofs + 2048) = make_uint2(cvtpk(b1.x,b1.y), cvtpk(b1.z,b1.w));
      *(uint2*)(nB + wofs + 4096) = make_uint2(cvtpk(b2.x,b2.y), cvtpk(b2.z,b2.w));
      *(uint2*)(nB + wofs + 6144) = make_uint2(cvtpk(b3.x,b3.y), cvtpk(b3.z,b3.w));
      __syncthreads();
    }
  }

  // partials: sp[bx][row][col], row = w*16 + fk*4 + r, col = n*16 + fr
  float* spb = sp + (u64)bx * (BATCH * NTOP);
  const int orow = row0 + w * 16 + fk * 4;
  #pragma unroll
  for (int n = 0; n < 4; ++n) {
    #pragma unroll
    for (int r = 0; r < 4; ++r)
      spb[(orow + r) * NTOP + ((n << 4) | fr)] = acc[n][r];
  }
}

// Epilogue: reduce 32 partials, then out = s + mu + RHO*(s @ theta_offdiag^T)
__global__ void __launch_bounds__(256) ctm_epi(const float* __restrict__ sp,
                                               const float* __restrict__ theta,
                                               const float* __restrict__ mu,
                                               float* __restrict__ out) {
  __shared__ float thT[NTOP * NTOP];   // thT[j*64+k] = theta[k][j]
  __shared__ float sb[8 * NTOP];
  const int t = threadIdx.x;
  const int r0 = blockIdx.x * 8;

  #pragma unroll
  for (int i = 0; i < 16; ++i) {
    int e = i * 256 + t;
    thT[(e & 63) * 64 + (e >> 6)] = theta[e];
  }

  const int k = t & 63;
  const int rl = t >> 6;
  #pragma unroll
  for (int rr = 0; rr < 2; ++rr) {
    const int r = rl + rr * 4;
    float sum = 0.f;
    #pragma unroll
    for (int cc = 0; cc < KSPLIT; ++cc)
      sum += sp[(u64)cc * (BATCH * NTOP) + (r0 + r) * NTOP + k];
    sb[r * 64 + k] = sum;
  }
  __syncthreads();

  const float muk = mu[k];
  const float diag = thT[k * 64 + k];
  #pragma unroll
  for (int rr = 0; rr < 2; ++rr) {
    const int r = rl + rr * 4;
    const float* srow = &sb[r * 64];
    float accv = 0.f;
    #pragma unroll 8
    for (int j = 0; j < 64; ++j)
      accv += thT[j * 64 + k] * srow[j];
    const float sv = srow[k];
    out[(r0 + r) * 64 + k] = sv + muk + RHO * (accv - diag * sv);
  }
}

extern "C" void kernel_launch(void* const* d_in, const int* in_sizes, int n_in,
                              void* d_out, int out_size, void* d_ws, size_t ws_size,
                              hipStream_t stream) {
  const float* x = (const float*)d_in[0];
  const float* beta = (const float*)d_in[1];
  const float* theta = (const float*)d_in[2];
  const float* mu = (const float*)d_in[3];
  float* out = (float*)d_out;

  // ws: s_part f32 [KSPLIT][BATCH][NTOP] = 16.78MB; fully written each launch.
  float* sp = (float*)d_ws;

  ctm_gemm<<<dim3(KSPLIT, BATCH / 64), 256, 0, stream>>>(x, beta, sp);
  ctm_epi<<<BATCH / 8, 256, 0, stream>>>(sp, theta, mu, out);
}